// Round 7
// baseline (120.495 us; speedup 1.0000x reference)
//
#include <hip/hip_runtime.h>
#include <hip/hip_fp16.h>

#define CH 16
#define HH 512
#define WW 960
#define HW (HH * WW)

#define TR 8      // output rows per block
#define TC 64     // output cols per block
#define RROWS 18  // staged rows [y0b-9, y0b+8]
#define RCOLS 136 // staged cols [x0b-68, x0b+67]
#define NSLOT (RROWS * RCOLS)  // one uint4 (8 ch f16) per pixel per pass

typedef __fp16 v2hf __attribute__((ext_vector_type(2)));   // builtin's type
typedef _Float16 h2r __attribute__((ext_vector_type(2)));  // arithmetic type

// one v_cvt_pkrtz_f16_f32: packs 2 f32 -> 2 f16 (RTZ) in one op
__device__ __forceinline__ unsigned pkrtz_u(float a, float b) {
  v2hf r = __builtin_amdgcn_cvt_pkrtz(a, b);
  return __builtin_bit_cast(unsigned, r);
}
__device__ __forceinline__ __half2 u2h(unsigned u) {
  return __builtin_bit_cast(__half2, u);
}

// ---------------------------------------------------------------------------
// Fused, chunk-split two-pass. Block = 8 rows x 64 cols = 512 thr, thread =
// one output pixel. Per pass: stage an 18x136 patch of 8 f16 channels
// (39168 B LDS -> 4 blocks/CU), gather 9 neighbors x 4 bilinear corners
// (one ds_read_b128 each), packed-f16 FMA, fold to f32 per di-row.
// ---------------------------------------------------------------------------
__global__ __launch_bounds__(512, 8) void recon_fused_f16(
    const float* __restrict__ img,   // [16][512][960] f32
    const float* __restrict__ offx,  // [512][960]
    const float* __restrict__ offy,  // [512][960]
    float* __restrict__ out) {       // [16][512][960]
  __shared__ uint4 lds[NSLOT];  // 39168 B

  // XCD swizzle: 960 blocks = 8 XCDs x 120; XCD k owns a 64-row band.
  const int hwid = blockIdx.x + blockIdx.y * 15;
  const int tile = (hwid & 7) * 120 + (hwid >> 3);
  const int tx = tile % 15, ty = tile / 15;
  const int x0b = tx * TC, y0b = ty * TR;
  const int tid = threadIdx.x;
  const int ylo = y0b - 9, xlo = x0b - 68;

  const int pixl = tid & 63;
  const int rowl = tid >> 6;  // 0..7
  const int x = x0b + pixl;
  const int y = y0b + rowl;
  const int po = y * WW + x;

  const float fxs = (float)(WW - 1) / (float)WW;
  const float fys = (float)(HH - 1) / (float)HH;
  const float s = 1.0f / 9.0f;

#pragma unroll
  for (int chunk = 0; chunk < 2; ++chunk) {
    // ---------------- stage: 8 channels as f16 HWC ----------------
#pragma unroll
    for (int it = 0; it < 5; ++it) {
      const int f = it * 512 + tid;
      if (f < NSLOT) {
        const int row = f / RCOLS;
        const int col = f - row * RCOLS;
        const int gr = min(max(ylo + row, 0), HH - 1);
        const int gc = min(max(xlo + col, 0), WW - 1);
        const float* src = img + (chunk * 8) * HW + gr * WW + gc;
        uint4 o;
        o.x = pkrtz_u(src[0 * HW], src[1 * HW]);
        o.y = pkrtz_u(src[2 * HW], src[3 * HW]);
        o.z = pkrtz_u(src[4 * HW], src[5 * HW]);
        o.w = pkrtz_u(src[6 * HW], src[7 * HW]);
        lds[f] = o;
      }
    }
    __syncthreads();

    // ---------------- gather + packed-f16 blend ----------------
    float acc[8];
#pragma unroll
    for (int i = 0; i < 8; ++i) acc[i] = 0.f;

#pragma unroll
    for (int di = -1; di <= 1; ++di) {
      int rr = y + di;
      rr = (rr < 0) ? 1 : ((rr >= HH) ? (HH - 2) : rr);  // reflect pad=1
      __half2 h[4];  // packed partial, <=3 terms before f32 fold
#pragma unroll
      for (int i = 0; i < 4; ++i) h[i] = u2h(0u);

#pragma unroll
      for (int dj = -1; dj <= 1; ++dj) {
        int cc = x + dj;
        cc = (cc < 0) ? 1 : ((cc >= WW) ? (WW - 2) : cc);
        const int o = rr * WW + cc;
        const float sx = offx[o];
        const float sy = offy[o];
        const float cx = fminf(fmaxf((float)x - sx, 0.0f), (float)(WW - 1));
        const float cy = fminf(fmaxf((float)y - sy, 0.0f), (float)(HH - 1));
        const float ix = cx * fxs;  // [0, W-1): x1 stays inside the patch
        const float iy = cy * fys;
        const float fx0 = floorf(ix);
        const float fy0 = floorf(iy);
        const float wx1 = ix - fx0, wx0 = 1.0f - wx1;
        const float wy1 = iy - fy0, wy0 = 1.0f - wy1;
        const int u00 = ((int)fy0 - ylo) * RCOLS + ((int)fx0 - xlo);

        const __half2 w00 = u2h(pkrtz_u(wx0 * wy0, wx0 * wy0));
        const __half2 w10 = u2h(pkrtz_u(wx1 * wy0, wx1 * wy0));
        const __half2 w01 = u2h(pkrtz_u(wx0 * wy1, wx0 * wy1));
        const __half2 w11 = u2h(pkrtz_u(wx1 * wy1, wx1 * wy1));

#define CORNER(UIDX, Wh)                          \
  {                                               \
    const uint4 q = lds[(UIDX)];                  \
    h[0] = __hfma2(u2h(q.x), (Wh), h[0]);         \
    h[1] = __hfma2(u2h(q.y), (Wh), h[1]);         \
    h[2] = __hfma2(u2h(q.z), (Wh), h[2]);         \
    h[3] = __hfma2(u2h(q.w), (Wh), h[3]);         \
  }
        CORNER(u00, w00)
        CORNER(u00 + 1, w10)
        CORNER(u00 + RCOLS, w01)
        CORNER(u00 + RCOLS + 1, w11)
#undef CORNER
      }
#pragma unroll
      for (int i = 0; i < 4; ++i) {
        const h2r a = __builtin_bit_cast(h2r, h[i]);
        acc[2 * i]     += (float)a.x;
        acc[2 * i + 1] += (float)a.y;
      }
    }

#pragma unroll
    for (int j = 0; j < 8; ++j) out[(chunk * 8 + j) * HW + po] = acc[j] * s;

    if (chunk == 0) __syncthreads();  // protect LDS before re-stage
  }
}

extern "C" void kernel_launch(void* const* d_in, const int* in_sizes, int n_in,
                              void* d_out, int out_size, void* d_ws, size_t ws_size,
                              hipStream_t stream) {
  const float* right = (const float*)d_in[0];  // [1,16,512,960]
  const float* offx  = (const float*)d_in[1];  // [1,1,512,960]
  const float* offy  = (const float*)d_in[2];  // [1,1,512,960]
  float* out = (float*)d_out;

  const dim3 grid(WW / TC, HH / TR);  // 15 x 64 = 960 blocks
  recon_fused_f16<<<grid, 512, 0, stream>>>(right, offx, offy, out);
}

// Round 8
// 111.659 us; speedup vs baseline: 1.0791x; 1.0791x over previous
//
#include <hip/hip_runtime.h>
#include <hip/hip_fp16.h>

#define CH 16
#define HH 512
#define WW 960
#define HW (HH * WW)

#define TR 8      // output rows per block
#define TC 64     // output cols per block
#define RROWS 18  // staged rows [y0b-9, y0b+8]
#define RCOLS 136 // staged cols [x0b-68, x0b+67]
#define NSLOT (RROWS * RCOLS)  // one uint4 (8 ch f16) per pixel per pass

typedef __fp16 v2hf __attribute__((ext_vector_type(2)));   // builtin's type
typedef _Float16 h2r __attribute__((ext_vector_type(2)));  // arithmetic type

// one v_cvt_pkrtz_f16_f32: packs 2 f32 -> 2 f16 (RTZ) in one op
__device__ __forceinline__ unsigned pkrtz_u(float a, float b) {
  v2hf r = __builtin_amdgcn_cvt_pkrtz(a, b);
  return __builtin_bit_cast(unsigned, r);
}
__device__ __forceinline__ __half2 u2h(unsigned u) {
  return __builtin_bit_cast(__half2, u);
}

// ---------------------------------------------------------------------------
// Fused, chunk-split two-pass, neighbor-setup HOISTED.
// Block = 8 rows x 64 cols = 512 thr, thread = one output pixel.
// Setup (once): 9 neighbors -> LDS base u00 + 4 bilinear weights packed into
//   2x half2 (27 VGPR state).
// Per pass: stage 18x136 patch of 8 f16 channels (39168 B -> up to 4
//   blocks/CU), then 9x4 ds_read_b128 gathers + packed-f16 FMA, fold to f32.
// ---------------------------------------------------------------------------
__global__ __launch_bounds__(512, 6) void recon_fused_f16(
    const float* __restrict__ img,   // [16][512][960] f32
    const float* __restrict__ offx,  // [512][960]
    const float* __restrict__ offy,  // [512][960]
    float* __restrict__ out) {       // [16][512][960]
  __shared__ uint4 lds[NSLOT];  // 39168 B

  // XCD swizzle: 960 blocks = 8 XCDs x 120; XCD k owns a 64-row band.
  const int hwid = blockIdx.x + blockIdx.y * 15;
  const int tile = (hwid & 7) * 120 + (hwid >> 3);
  const int tx = tile % 15, ty = tile / 15;
  const int x0b = tx * TC, y0b = ty * TR;
  const int tid = threadIdx.x;
  const int ylo = y0b - 9, xlo = x0b - 68;

  const int pixl = tid & 63;
  const int rowl = tid >> 6;  // 0..7
  const int x = x0b + pixl;
  const int y = y0b + rowl;
  const int po = y * WW + x;

  const float fxs = (float)(WW - 1) / (float)WW;
  const float fys = (float)(HH - 1) / (float)HH;
  const float s = 1.0f / 9.0f;

  // ---------------- hoisted per-neighbor setup (done ONCE) ----------------
  int u00a[9];      // LDS slot index of corner (x0,y0)
  __half2 wxa[9];   // packed (w00, w10)
  __half2 wya[9];   // packed (w01, w11)
#pragma unroll
  for (int di = -1; di <= 1; ++di) {
    int rr = y + di;
    rr = (rr < 0) ? 1 : ((rr >= HH) ? (HH - 2) : rr);  // reflect pad=1
#pragma unroll
    for (int dj = -1; dj <= 1; ++dj) {
      const int n = (di + 1) * 3 + (dj + 1);
      int cc = x + dj;
      cc = (cc < 0) ? 1 : ((cc >= WW) ? (WW - 2) : cc);
      const int o = rr * WW + cc;
      const float sx = offx[o];
      const float sy = offy[o];
      const float cx = fminf(fmaxf((float)x - sx, 0.0f), (float)(WW - 1));
      const float cy = fminf(fmaxf((float)y - sy, 0.0f), (float)(HH - 1));
      const float ix = cx * fxs;  // [0, W-1): x1 stays inside the patch
      const float iy = cy * fys;
      const float fx0 = floorf(ix);
      const float fy0 = floorf(iy);
      const float wx1 = ix - fx0, wx0 = 1.0f - wx1;
      const float wy1 = iy - fy0, wy0 = 1.0f - wy1;
      u00a[n] = ((int)fy0 - ylo) * RCOLS + ((int)fx0 - xlo);
      wxa[n] = u2h(pkrtz_u(wx0 * wy0, wx1 * wy0));  // (w00, w10)
      wya[n] = u2h(pkrtz_u(wx0 * wy1, wx1 * wy1));  // (w01, w11)
    }
  }

#pragma unroll
  for (int chunk = 0; chunk < 2; ++chunk) {
    // ---------------- stage: 8 channels as f16 HWC ----------------
#pragma unroll
    for (int it = 0; it < 5; ++it) {
      const int f = it * 512 + tid;
      if (f < NSLOT) {
        const int row = f / RCOLS;
        const int col = f - row * RCOLS;
        const int gr = min(max(ylo + row, 0), HH - 1);
        const int gc = min(max(xlo + col, 0), WW - 1);
        const float* src = img + (chunk * 8) * HW + gr * WW + gc;
        uint4 o;
        o.x = pkrtz_u(src[0 * HW], src[1 * HW]);
        o.y = pkrtz_u(src[2 * HW], src[3 * HW]);
        o.z = pkrtz_u(src[4 * HW], src[5 * HW]);
        o.w = pkrtz_u(src[6 * HW], src[7 * HW]);
        lds[f] = o;
      }
    }
    __syncthreads();

    // ---------------- gather + packed-f16 blend ----------------
    float acc[8];
#pragma unroll
    for (int i = 0; i < 8; ++i) acc[i] = 0.f;

#pragma unroll
    for (int di = 0; di < 3; ++di) {
      __half2 h[4];  // packed partial, <=3 neighbors before f32 fold
#pragma unroll
      for (int i = 0; i < 4; ++i) h[i] = u2h(0u);

#pragma unroll
      for (int dj = 0; dj < 3; ++dj) {
        const int n = di * 3 + dj;
        const int u00 = u00a[n];
        const __half2 w00 = __half2half2(__low2half(wxa[n]));
        const __half2 w10 = __half2half2(__high2half(wxa[n]));
        const __half2 w01 = __half2half2(__low2half(wya[n]));
        const __half2 w11 = __half2half2(__high2half(wya[n]));

#define CORNER(UIDX, Wh)                          \
  {                                               \
    const uint4 q = lds[(UIDX)];                  \
    h[0] = __hfma2(u2h(q.x), (Wh), h[0]);         \
    h[1] = __hfma2(u2h(q.y), (Wh), h[1]);         \
    h[2] = __hfma2(u2h(q.z), (Wh), h[2]);         \
    h[3] = __hfma2(u2h(q.w), (Wh), h[3]);         \
  }
        CORNER(u00, w00)
        CORNER(u00 + 1, w10)
        CORNER(u00 + RCOLS, w01)
        CORNER(u00 + RCOLS + 1, w11)
#undef CORNER
      }
#pragma unroll
      for (int i = 0; i < 4; ++i) {
        const h2r a = __builtin_bit_cast(h2r, h[i]);
        acc[2 * i]     += (float)a.x;
        acc[2 * i + 1] += (float)a.y;
      }
    }

#pragma unroll
    for (int j = 0; j < 8; ++j) out[(chunk * 8 + j) * HW + po] = acc[j] * s;

    if (chunk == 0) __syncthreads();  // protect LDS before re-stage
  }
}

extern "C" void kernel_launch(void* const* d_in, const int* in_sizes, int n_in,
                              void* d_out, int out_size, void* d_ws, size_t ws_size,
                              hipStream_t stream) {
  const float* right = (const float*)d_in[0];  // [1,16,512,960]
  const float* offx  = (const float*)d_in[1];  // [1,1,512,960]
  const float* offy  = (const float*)d_in[2];  // [1,1,512,960]
  float* out = (float*)d_out;

  const dim3 grid(WW / TC, HH / TR);  // 15 x 64 = 960 blocks
  recon_fused_f16<<<grid, 512, 0, stream>>>(right, offx, offy, out);
}